// Round 1
// baseline (1039.834 us; speedup 1.0000x reference)
//
#include <hip/hip_runtime.h>

// FiberConv: out[b, t*OUT+o] = sum_{s,i} kernel[t,s,o,i] * x[b, s*IN+i] + bias[o]
// GEMM: X[400000 x 384] * B^T, B[n=t*32+o][k=s*32+i]. f32 I/O, bf16 MFMA inside.
// v2: fragment-ordered B + LDS double-buffer staging (global_load_lds w16,
//     counted vmcnt, raw barriers) + swapped MFMA operands for f32x4 stores.

using f32x4  = __attribute__((ext_vector_type(4))) float;
using bf16x8 = __attribute__((ext_vector_type(8))) __bf16;
using short8 = __attribute__((ext_vector_type(8))) short;

constexpr int T_   = 12;
constexpr int S_   = 12;
constexpr int ATTR = 3;
constexpr int IN   = 32;
constexpr int OUT  = 32;
constexpr int K    = S_ * IN;    // 384
constexpr int N    = T_ * OUT;   // 384
constexpr int NB   = 400000;     // batch rows (3125 * 128 exact)
constexpr int KB_CNT = K / 32;   // 12 MFMA K-steps
constexpr int CT_CNT = N / 16;   // 24 channel tiles of 16
constexpr int FRAG_SHORTS = 64 * 8;              // 512 shorts = 1024 B per (ct,kb) fragment
constexpr int CT_SHORTS   = KB_CNT * FRAG_SHORTS; // 6144 shorts = 12 KB per ct

__device__ __forceinline__ unsigned short f2bf(float f) {
  unsigned u = __builtin_bit_cast(unsigned, f);
  u += 0x7fffu + ((u >> 16) & 1u);
  return (unsigned short)(u >> 16);
}

// Emit B in MFMA A-operand fragment order:
//   frag index = ((ct*12 + kb)*64 + lane)*8 + j
//   where n = ct*16 + (lane&15), k = kb*32 + (lane>>4)*8 + j.
// Hot-loop loads then read contiguous 1 KB per (ct,kb).
__global__ __launch_bounds__(384) void build_B(const float* __restrict__ edge,
                                               const float* __restrict__ W,
                                               unsigned short* __restrict__ Bm) {
  const int n = blockIdx.x;   // 0..383  (t*32+o)
  const int k = threadIdx.x;  // 0..383  (s*32+i)
  const int t = n >> 5, o = n & 31;
  const int s = k >> 5, i = k & 31;
  const float* e = edge + (t * S_ + s) * ATTR;
  const float* w = W + (o * IN + i) * ATTR;
  const float v = e[0] * w[0] + e[1] * w[1] + e[2] * w[2];
  const int ct = n >> 4, l15 = n & 15;
  const int kb = k >> 5, quad = (k >> 3) & 3, j = k & 7;
  const int lane = (quad << 4) | l15;
  Bm[((ct * KB_CNT + kb) * 64 + lane) * 8 + j] = f2bf(v);
}

// Stage one ct-tile (12 KB = 12 chunks of 1024 B) into LDS; wave wid covers
// chunks [wid*3, wid*3+3). LDS dest is wave-uniform base + lane*16 (linear),
// global src is per-lane — both sides linear (rule: both-or-neither swizzle).
__device__ __forceinline__ void stage_B(const unsigned short* __restrict__ Bm, int ct,
                                        unsigned short* dst, int wid, int lane) {
  const unsigned short* src = Bm + (size_t)ct * CT_SHORTS;
#pragma unroll
  for (int q = 0; q < 3; ++q) {
    const int c = wid * 3 + q;
    __builtin_amdgcn_global_load_lds(
        (const __attribute__((address_space(1))) void*)(src + c * FRAG_SHORTS + lane * 8),
        (__attribute__((address_space(3))) void*)(dst + c * FRAG_SHORTS),
        16, 0, 0);
  }
}

// 4 waves/block, 32 batch rows/wave (2 N-tiles of 16), loop 24 channel tiles.
// MFMA operands SWAPPED vs v1: A = B-matrix rows (channels = M), B = x rows
// (batch = N). C layout then gives each lane 4 CONSECUTIVE channels -> f32x4 store.
__global__ __launch_bounds__(256, 2) void fiber_gemm(
    const float* __restrict__ x, const unsigned short* __restrict__ Bm,
    const float* __restrict__ bias, float* __restrict__ out) {
  __shared__ __align__(16) unsigned short Bl[2][CT_SHORTS];  // 2 x 12 KB double buffer

  const int lane = threadIdx.x & 63;
  const int wid  = threadIdx.x >> 6;
  const int col  = lane & 15;   // batch row within 16-tile (MFMA N)
  const int quad = lane >> 4;   // k-subchunk / C channel-group
  const int rowbase = blockIdx.x * 128 + wid * 32;

  // Issue first B-tile staging as early as possible.
  stage_B(Bm, 0, &Bl[0][0], wid, lane);
  __builtin_amdgcn_sched_barrier(0);

  // ---- X fragments (MFMA B-operand), whole K in registers. Layout identical
  // to v1's A-operand: row = col, k = quad*8 + j. 96 VGPRs.
  bf16x8 Xf[2][KB_CNT];
#pragma unroll
  for (int mt = 0; mt < 2; ++mt) {
    const float* xp = x + (size_t)(rowbase + mt * 16 + col) * K + quad * 8;
#pragma unroll
    for (int kb = 0; kb < KB_CNT; ++kb) {
      const f32x4 lo = *(const f32x4*)(xp + kb * 32);
      const f32x4 hi = *(const f32x4*)(xp + kb * 32 + 4);
      short8 sv;
#pragma unroll
      for (int j = 0; j < 4; ++j) {
        sv[j]     = (short)f2bf(lo[j]);
        sv[j + 4] = (short)f2bf(hi[j]);
      }
      Xf[mt][kb] = __builtin_bit_cast(bf16x8, sv);
    }
  }

  // Per-lane bias vectors: channel = ct*16 + quad*4 + r, o = channel & 31.
  // ct even -> o = quad*4+r; ct odd -> o = 16+quad*4+r.
  f32x4 bv0, bv1;
#pragma unroll
  for (int r = 0; r < 4; ++r) {
    bv0[r] = bias[quad * 4 + r];
    bv1[r] = bias[16 + quad * 4 + r];
  }

  // Wait staging of ct=0 (and X loads), then enter steady state.
  asm volatile("s_waitcnt vmcnt(0)" ::: "memory");
  __builtin_amdgcn_s_barrier();

#pragma unroll 1
  for (int ct = 0; ct < CT_CNT; ++ct) {
    const int cur = ct & 1;
    if (ct + 1 < CT_CNT) {
      stage_B(Bm, ct + 1, &Bl[cur ^ 1][0], wid, lane);
      __builtin_amdgcn_sched_barrier(0);  // pin stage loads before compute/stores
    }

    f32x4 acc0 = {0.f, 0.f, 0.f, 0.f};
    f32x4 acc1 = {0.f, 0.f, 0.f, 0.f};
    const unsigned short* bp = &Bl[cur][lane * 8];
#pragma unroll
    for (int kb = 0; kb < KB_CNT; ++kb) {
      const bf16x8 Bf = *(const bf16x8*)(bp + kb * FRAG_SHORTS);  // contiguous, conflict-free
      acc0 = __builtin_amdgcn_mfma_f32_16x16x32_bf16(Bf, Xf[0][kb], acc0, 0, 0, 0);
      acc1 = __builtin_amdgcn_mfma_f32_16x16x32_bf16(Bf, Xf[1][kb], acc1, 0, 0, 0);
    }

    // C layout (swapped): col = lane&15 = batch row, row = quad*4+r = channel.
    // Lane's 4 acc values are 4 consecutive channels -> one dwordx4 per M-half.
    const f32x4 bv = cur ? bv1 : bv0;
    float* op0 = out + (size_t)(rowbase + col) * N + ct * 16 + quad * 4;
    *(f32x4*)op0            = acc0 + bv;  // rows rowbase + col
    *(f32x4*)(op0 + 16 * N) = acc1 + bv;  // rows rowbase + 16 + col

    if (ct + 1 < CT_CNT) {
      // Wait only the 3 stage loads (oldest); leave the 2 stores in flight.
      asm volatile("s_waitcnt vmcnt(2)" ::: "memory");
      __builtin_amdgcn_s_barrier();
    }
  }
}

extern "C" void kernel_launch(void* const* d_in, const int* in_sizes, int n_in,
                              void* d_out, int out_size, void* d_ws, size_t ws_size,
                              hipStream_t stream) {
  const float* x    = (const float*)d_in[0];  // [B, S, IN] f32
  const float* edge = (const float*)d_in[1];  // [T, S, ATTR] f32
  const float* W    = (const float*)d_in[2];  // [OUT*IN, ATTR] f32
  const float* bias = (const float*)d_in[3];  // [OUT] f32
  float* out = (float*)d_out;                 // [B, T*OUT] f32
  unsigned short* Bm = (unsigned short*)d_ws; // 384*384 bf16 = 294912 B scratch

  build_B<<<dim3(N), dim3(K), 0, stream>>>(edge, W, Bm);
  fiber_gemm<<<dim3(NB / 128), dim3(256), 0, stream>>>(x, Bm, bias, out);
}